// Round 4
// baseline (413.941 us; speedup 1.0000x reference)
//
#include <hip/hip_runtime.h>

#define ND 64
#define NPAIR 6

typedef short bf16x8 __attribute__((ext_vector_type(8)));
typedef float floatx4 __attribute__((ext_vector_type(4)));

static constexpr int SPB  = 8;             // samples per block
static constexpr int ROWS = SPB * NPAIR;   // 48 rows = 3 waves x 16 (B-operand n-cols)

__device__ __forceinline__ unsigned short f2bf(float f) {
    unsigned u = __builtin_bit_cast(unsigned, f);
    u += 0x7FFFu + ((u >> 16) & 1u);       // RNE (no NaN inputs)
    return (unsigned short)(u >> 16);
}
__device__ __forceinline__ unsigned f2bf2(float lo, float hi) {
    return (unsigned)f2bf(lo) | ((unsigned)f2bf(hi) << 16);
}
__device__ __forceinline__ unsigned relupack2(float a, float ba, float b, float bb) {
    float u = a + ba; u = u > 0.f ? u : 0.f;
    float v = b + bb; v = v > 0.f ? v : 0.f;
    return f2bf2(u, v);
}
// XOR chunk swizzles (chunk = 8 halfwords = 16B), same family R3 verified
__device__ __forceinline__ int swzAx(int row, int c) { return (c & 8) | ((c ^ row) & 7); } // c 0..15
__device__ __forceinline__ int swzD (int row, int c) { return (c ^ row) & 7; }             // c 0..7

// Repack W1..3 into A-operand fragments for D = W*Act with channel permutation
// pi(ot,m) = 32*(ot>>1) + 8*(m>>2) + 4*(ot&1) + (m&3)  (m = quad*4+reg of C-layout)
// Layout: P[(((L*4+ot)*6 + c)*64 + lane)*8 + j]; lane=(q*16+m): element k = c*32 + q*8 + j
// k<128: x-part (i=k>>1, kk=k&1); k>=128: d-part (i=k-128, kk=2)
__global__ void repack_w(const float* __restrict__ W1, const float* __restrict__ W2,
                         const float* __restrict__ W3, unsigned short* __restrict__ P) {
    int idx = blockIdx.x * 256 + threadIdx.x;
    if (idx >= 3 * 4 * 6 * 64 * 8) return;   // 36864
    int j    = idx & 7;
    int lane = (idx >> 3) & 63;
    int g    = idx >> 9;                     // (L*4+ot)*6 + c
    int c    = g % 6;
    int ot   = (g / 6) & 3;
    int L    = g / 24;
    int m = lane & 15, q = lane >> 4;
    int ch = 32 * (ot >> 1) + 8 * (m >> 2) + 4 * (ot & 1) + (m & 3);
    int k  = c * 32 + q * 8 + j;
    const float* W = (L == 0) ? W1 : (L == 1) ? W2 : W3;
    float v = (k < 128) ? W[ch * 192 + (k >> 1) * 3 + (k & 1)]
                        : W[ch * 192 + (k - 128) * 3 + 2];
    P[idx] = f2bf(v);
}

// 3 waves x 16 rows. Layer loop: zero LDS, zero barriers — W streamed from L1/L2 as
// A-operand, activations live in registers as B-operand; d-part chains in-register.
__global__ __launch_bounds__(192, 5) void dijet_main(
    const float* __restrict__ x, const float* __restrict__ d,
    const float* __restrict__ b1, const float* __restrict__ b2,
    const float* __restrict__ b3, const unsigned short* __restrict__ Wa,
    float* __restrict__ out)
{
    // Xs[48][128] x-part + Ds[48][64] d, both chunk-swizzled. Dead after frag load;
    // overlaid by Co (out transpose, padded stride 390 floats) in the epilogue.
    __shared__ __align__(16) unsigned short SMEM[ROWS * 128 + ROWS * 64]; // 18432 B
    unsigned short* Xs = SMEM;
    unsigned short* Ds = SMEM + ROWS * 128;
    float* Co = (float*)SMEM;

    const int t   = threadIdx.x;           // 0..191
    const int b0  = blockIdx.x * SPB;
    const int wv  = t >> 6;
    const int lane = t & 63;
    const int l15 = lane & 15;
    const int q   = lane >> 4;

    // ---- stage d: 8 float2/thread, coalesced; residual kept in regs
    float2 dres[8];
    {
        const float2* d2 = (const float2*)(d + (size_t)b0 * 384);
        #pragma unroll
        for (int m = 0; m < 8; ++m) dres[m] = d2[m * 192 + t];
        const int i = t / 3;                       // channel 0..63
        const int s = 2 * (t - 3 * (t / 3));       // slot 0,2,4
        #pragma unroll
        for (int m = 0; m < 8; ++m) {
            int row0 = m * 6 + s, row1 = row0 + 1;
            Ds[row0 * 64 + swzD(row0, i >> 3) * 8 + (i & 7)] = f2bf(dres[m].x);
            Ds[row1 * 64 + swzD(row1, i >> 3) * 8 + (i & 7)] = f2bf(dres[m].y);
        }
    }
    // ---- stage x: 8 float4/thread, coalesced (sample == m); convert + swizzled scatter
    {
        const float4* x4 = (const float4*)(x + (size_t)b0 * 768);
        const int i  = t / 3;                      // channel 0..63
        const int sl = (t - 3 * (t / 3)) * 2;      // slot 0,2,4
        const int c16 = i >> 2;                    // 16B chunk of j=2i
        const int iw  = i & 3;
        unsigned* Xs32 = (unsigned*)Xs;
        #pragma unroll
        for (int m = 0; m < 8; ++m) {
            float4 v = x4[m * 192 + t];
            int row0 = m * 6 + sl, row1 = row0 + 1;
            Xs32[row0 * 64 + swzAx(row0, c16) * 4 + iw] = f2bf2(v.x, v.y);
            Xs32[row1 * 64 + swzAx(row1, c16) * 4 + iw] = f2bf2(v.z, v.w);
        }
    }
    __syncthreads();

    // ---- persistent B-fragments (this wave's 16 rows); Xs/Ds dead afterwards
    const int r = wv * 16 + l15;                   // lane's sample-row (n-col)
    bf16x8 Bx[4], Bd0, Bd1;
    #pragma unroll
    for (int kk = 0; kk < 4; ++kk)
        Bx[kk] = *(const bf16x8*)(Xs + r * 128 + swzAx(r, kk * 4 + q) * 8);
    Bd0 = *(const bf16x8*)(Ds + r * 64 + swzD(r, q) * 8);       // d-ch 8q..8q+7
    Bd1 = *(const bf16x8*)(Ds + r * 64 + swzD(r, 4 + q) * 8);   // d-ch 32+8q..+7

    const int rb = r / 6;                          // sample within block
    const int rs = r - 6 * rb;                     // slot

    #pragma unroll
    for (int L = 0; L < 3; ++L) {
        const float* bL = (L == 0) ? b1 : (L == 1) ? b2 : b3;
        const unsigned short* WL = Wa + L * 12288 + lane * 8;

        floatx4 acc[4];
        #pragma unroll
        for (int ot = 0; ot < 4; ++ot) {
            const unsigned short* wt = WL + ot * 3072;
            floatx4 a = {0.f, 0.f, 0.f, 0.f};
            a = __builtin_amdgcn_mfma_f32_16x16x32_bf16(*(const bf16x8*)(wt),        Bx[0], a, 0, 0, 0);
            a = __builtin_amdgcn_mfma_f32_16x16x32_bf16(*(const bf16x8*)(wt + 512),  Bx[1], a, 0, 0, 0);
            a = __builtin_amdgcn_mfma_f32_16x16x32_bf16(*(const bf16x8*)(wt + 1024), Bx[2], a, 0, 0, 0);
            a = __builtin_amdgcn_mfma_f32_16x16x32_bf16(*(const bf16x8*)(wt + 1536), Bx[3], a, 0, 0, 0);
            a = __builtin_amdgcn_mfma_f32_16x16x32_bf16(*(const bf16x8*)(wt + 2048), Bd0,   a, 0, 0, 0);
            a = __builtin_amdgcn_mfma_f32_16x16x32_bf16(*(const bf16x8*)(wt + 2560), Bd1,   a, 0, 0, 0);
            acc[ot] = a;
        }

        // lane (q,l15) holds channels {8q+j, 32+8q+j} of row r: ch(ot,reg)=32*(ot>>1)+8q+4*(ot&1)+reg
        const float4* bv4 = (const float4*)bL;
        const float4 bl0 = bv4[2 * q],     bl1 = bv4[2 * q + 1];
        const float4 bh0 = bv4[8 + 2 * q], bh1 = bv4[8 + 2 * q + 1];

        if (L < 2) {
            // next layer's d-part B-frags: pure in-register repack (+bias+relu)
            union { bf16x8 h; unsigned u[4]; } p0, p1;
            p0.u[0] = relupack2(acc[0][0], bl0.x, acc[0][1], bl0.y);
            p0.u[1] = relupack2(acc[0][2], bl0.z, acc[0][3], bl0.w);
            p0.u[2] = relupack2(acc[1][0], bl1.x, acc[1][1], bl1.y);
            p0.u[3] = relupack2(acc[1][2], bl1.z, acc[1][3], bl1.w);
            p1.u[0] = relupack2(acc[2][0], bh0.x, acc[2][1], bh0.y);
            p1.u[1] = relupack2(acc[2][2], bh0.z, acc[2][3], bh0.w);
            p1.u[2] = relupack2(acc[3][0], bh1.x, acc[3][1], bh1.y);
            p1.u[3] = relupack2(acc[3][2], bh1.z, acc[3][3], bh1.w);
            Bd0 = p0.h; Bd1 = p1.h;
        } else {
            __syncthreads();                       // all waves done with Xs/Ds; Co overlay safe
            // Co[b*390 + ch*6 + s] (+6 pad per sample kills same-bank rows)
            float* cb = Co + rb * 390 + rs + (8 * q) * 6;
            cb[0]   = acc[0][0] + bl0.x; cb[6]   = acc[0][1] + bl0.y;
            cb[12]  = acc[0][2] + bl0.z; cb[18]  = acc[0][3] + bl0.w;
            cb[24]  = acc[1][0] + bl1.x; cb[30]  = acc[1][1] + bl1.y;
            cb[36]  = acc[1][2] + bl1.z; cb[42]  = acc[1][3] + bl1.w;
            cb[192] = acc[2][0] + bh0.x; cb[198] = acc[2][1] + bh0.y;
            cb[204] = acc[2][2] + bh0.z; cb[210] = acc[2][3] + bh0.w;
            cb[216] = acc[3][0] + bh1.x; cb[222] = acc[3][1] + bh1.y;
            cb[228] = acc[3][2] + bh1.z; cb[234] = acc[3][3] + bh1.w;
            __syncthreads();
            // coalesced stores fused with register-resident residual + final relu
            float2* out2 = (float2*)(out + (size_t)b0 * 384);
            #pragma unroll
            for (int m = 0; m < 8; ++m) {
                float2 c = *(const float2*)(Co + m * 390 + 2 * t);
                float2 rv;
                rv.x = c.x + dres[m].x; rv.x = rv.x > 0.f ? rv.x : 0.f;
                rv.y = c.y + dres[m].y; rv.y = rv.y > 0.f ? rv.y : 0.f;
                out2[m * 192 + t] = rv;
            }
        }
    }
}

extern "C" void kernel_launch(void* const* d_in, const int* in_sizes, int n_in,
                              void* d_out, int out_size, void* d_ws, size_t ws_size,
                              hipStream_t stream)
{
    const float* x  = (const float*)d_in[0];
    const float* dd = (const float*)d_in[1];
    const float* W1 = (const float*)d_in[2];
    const float* b1 = (const float*)d_in[3];
    const float* W2 = (const float*)d_in[4];
    const float* b2 = (const float*)d_in[5];
    const float* W3 = (const float*)d_in[6];
    const float* b3 = (const float*)d_in[7];
    float* out = (float*)d_out;
    unsigned short* Wp = (unsigned short*)d_ws;   // 3*4*6*64*8*2 = 73728 B

    int n = in_sizes[0] / (ND * 12);              // 65536

    repack_w<<<144, 256, 0, stream>>>(W1, W2, W3, Wp);
    dijet_main<<<n / SPB, 192, 0, stream>>>(x, dd, b1, b2, b3, Wp, out);
}